// Round 8
// baseline (392.437 us; speedup 1.0000x reference)
//
#include <hip/hip_runtime.h>
#include <math.h>

#define HD 8192
#define ID 4096
#define KSEL 409           // int(8192 * 0.05)
#define LR 0.001f
#define NBLK 512
#define NTHR 256
#define ENC_BLKS 160       // blocks 1..160 do encoder; 161..511 do ssq; 0 does topk

typedef float f4 __attribute__((ext_vector_type(4)));
typedef float f2 __attribute__((ext_vector_type(2)));

// workspace layout (float indices)
#define WS_H     0                 // 8192 f32
#define WS_HS    8192              // 8192 f32
#define WS_IDX   16384             // 8192 i32
#define WS_VAL   24576             // 8192 f32
#define WS_SCAL  32768             // [0]=kth, [1]=inv_norm, [2](int)=n
#define WS_SSQ   32832             // 512 doubles, one per block (byte 131328, 8-aligned)
#define WS_FPART (32832 + 1024)    // 128 doubles: 32 blocks x {dy,sh2,l0,l1}
#define WS_BAR   (32832 + 1024 + 256)  // int index: [0]=global barrier, [1]=enc-done

__device__ __forceinline__ void gbar(unsigned* bar, unsigned target) {
    __syncthreads();
    if (threadIdx.x == 0) {
        __threadfence();                       // release our writes (device scope)
        atomicAdd(bar, 1u);
        while (atomicAdd(bar, 0u) < target) __builtin_amdgcn_s_sleep(4);
        __threadfence();                       // acquire others' writes
    }
    __syncthreads();
}

__global__ __launch_bounds__(NTHR, 2) void k_fused(
    const float* __restrict__ x,  const float* __restrict__ W,
    const float* __restrict__ b,  const float* __restrict__ S,
    const float* __restrict__ st, const float* __restrict__ Wc,
    const float* __restrict__ bc, float* __restrict__ out,
    float* __restrict__ ws) {
    __shared__ f4 smem4[2048];      // 32 KB, reused across phases
    __shared__ double sd[256];
    __shared__ int sred[4];
    __shared__ int wsum[4];
    const int tid = threadIdx.x;
    const int bid = blockIdx.x;
    unsigned* bar  = (unsigned*)ws + WS_BAR;
    unsigned* ctrA = (unsigned*)ws + WS_BAR + 1;

    // ========== PA: enc (blocks 1..160, NT loads) || ssq (161..511) || topk (0) ==========
    if (bid >= 1 && bid <= ENC_BLKS) {
        const f4* x4 = (const f4*)x;
        for (int k = tid; k < ID / 4; k += NTHR) smem4[k] = x4[k];
        __syncthreads();
        int wave = tid >> 6, lane = tid & 63;
        int wenc = (bid - 1) * 4 + wave;           // 0..639
        for (int row = wenc; row < HD; row += ENC_BLKS * 4) {
            const f4* w4 = (const f4*)(W + (size_t)row * ID);
            float acc = 0.f;
#pragma unroll
            for (int k = 0; k < 16; ++k) {
                f4 a  = __builtin_nontemporal_load(&w4[lane + 64 * k]);  // keep S in L3
                f4 xv = smem4[lane + 64 * k];
                acc += a.x * xv.x + a.y * xv.y + a.z * xv.z + a.w * xv.w;
            }
#pragma unroll
            for (int off = 32; off; off >>= 1) acc += __shfl_xor(acc, off, 64);
            if (lane == 0) {
                float h = acc + b[row];
                ws[WS_H + row] = h > 0.f ? h : 0.f;
            }
        }
        if (tid == 0) ((double*)(ws + WS_SSQ))[bid] = 0.0;
        __syncthreads();
        if (tid == 0) { __threadfence(); atomicAdd(ctrA, 1u); }  // signal enc done
    } else if (bid > ENC_BLKS) {
        const f4* S4 = (const f4*)S;
        const int total4 = HD * HD / 4;            // 16777216
        const int stride = (NBLK - ENC_BLKS - 1) * NTHR;  // 351*256 = 89856
        double acc = 0.0;
        for (int i = (bid - ENC_BLKS - 1) * NTHR + tid; i < total4; i += stride) {
            f4 v = S4[i];                          // normal load: warm L3 with S
            acc += (double)(v.x * v.x + v.y * v.y) + (double)(v.z * v.z + v.w * v.w);
        }
        sd[tid] = acc;
        __syncthreads();
        for (int s = 128; s; s >>= 1) {
            if (tid < s) sd[tid] += sd[tid + s];
            __syncthreads();
        }
        if (tid == 0) ((double*)(ws + WS_SSQ))[bid] = sd[0];
        __syncthreads();
    } else {  // bid == 0: wait for enc, then exact top-K + compaction
        if (tid == 0) {
            while (atomicAdd(ctrA, 0u) < (unsigned)ENC_BLKS) __builtin_amdgcn_s_sleep(2);
            __threadfence();
            ((double*)(ws + WS_SSQ))[0] = 0.0;
        }
        __syncthreads();
        float v[32];
        const f4* h4 = (const f4*)(ws + WS_H);
#pragma unroll
        for (int k = 0; k < 8; ++k) {
            f4 t = h4[tid * 8 + k];
            v[4 * k + 0] = t.x; v[4 * k + 1] = t.y; v[4 * k + 2] = t.z; v[4 * k + 3] = t.w;
        }
        // h >= 0 -> float order == uint bit order; exact Kth via bit binary search
        unsigned lo = 0u, hi = 0x7F800000u;
        while (hi - lo > 1u) {
            unsigned mid = (lo + hi) >> 1;
            float t = __uint_as_float(mid);
            int c = 0;
#pragma unroll
            for (int k = 0; k < 32; ++k) c += (v[k] >= t) ? 1 : 0;
#pragma unroll
            for (int off = 32; off; off >>= 1) c += __shfl_xor(c, off, 64);
            if ((tid & 63) == 0) sred[tid >> 6] = c;
            __syncthreads();
            int cnt = sred[0] + sred[1] + sred[2] + sred[3];
            __syncthreads();
            if (cnt >= KSEL) lo = mid; else hi = mid;
        }
        float kth = __uint_as_float(lo);

        int cnt_t = 0;
        f4* hs4 = (f4*)(ws + WS_HS);
#pragma unroll
        for (int k = 0; k < 8; ++k) {
            f4 o;
            o.x = (v[4 * k + 0] >= kth) ? v[4 * k + 0] : 0.f;
            o.y = (v[4 * k + 1] >= kth) ? v[4 * k + 1] : 0.f;
            o.z = (v[4 * k + 2] >= kth) ? v[4 * k + 2] : 0.f;
            o.w = (v[4 * k + 3] >= kth) ? v[4 * k + 3] : 0.f;
            hs4[tid * 8 + k] = o;
        }
#pragma unroll
        for (int k = 0; k < 32; ++k) cnt_t += ((v[k] >= kth) && (v[k] > 0.f)) ? 1 : 0;

        int c = cnt_t;
#pragma unroll
        for (int off = 1; off < 64; off <<= 1) {
            int y = __shfl_up(c, off, 64);
            if ((tid & 63) >= off) c += y;
        }
        if ((tid & 63) == 63) wsum[tid >> 6] = c;
        __syncthreads();
        int base = 0;
        for (int w = 0; w < (tid >> 6); ++w) base += wsum[w];
        int p = base + c - cnt_t;

        int* idx = ((int*)ws) + WS_IDX;
#pragma unroll
        for (int k = 0; k < 32; ++k) {
            float val = v[k];
            if ((val >= kth) && (val > 0.f)) {
                idx[p] = tid * 32 + k;
                ws[WS_VAL + p] = val;
                ++p;
            }
        }
        if (tid == 0) {
            ws[WS_SCAL + 0] = kth;
            ((int*)ws)[WS_SCAL + 2] = wsum[0] + wsum[1] + wsum[2] + wsum[3];
        }
        __syncthreads();
    }
    gbar(bar, 1u * NBLK);

    // ========= PB: blocks 0..31 -> y gather + tanh + out + dot partials =========
    if (bid < 32) {
        int n = ((const int*)ws)[WS_SCAL + 2];
        int* sidx = (int*)smem4;                 // 8 KB
        float* sval = (float*)(smem4 + 512);     // 8 KB at byte offset 8192
        int nl = n < 2048 ? n : 2048;
        for (int t = tid; t < nl; t += NTHR) {
            sidx[t] = ((const int*)ws)[WS_IDX + t];
            sval[t] = ws[WS_VAL + t];
        }
        __syncthreads();
        int j = bid * NTHR + tid;               // 0..8191
        float y = 0.f;
#pragma unroll 4
        for (int t = 0; t < n; ++t) {
            int   ii = (t < 2048) ? sidx[t] : ((const int*)ws)[WS_IDX + t];
            float vv = (t < 2048) ? sval[t] : ws[WS_VAL + t];
            y += vv * S[(size_t)ii * HD + j];   // L3-resident rows
        }
        float hsj = ws[WS_HS + j];
        float ns = tanhf(y + st[j]);
        out[2 + j] = ns;
        double red[4];
        red[0] = (double)(y * hsj);
        red[1] = (double)(hsj * hsj);
        red[2] = (double)(ns * Wc[j]);
        red[3] = (double)(ns * Wc[HD + j]);
        __syncthreads();
        for (int q = 0; q < 4; ++q) {
            sd[tid] = red[q];
            __syncthreads();
            for (int s = 128; s; s >>= 1) {
                if (tid < s) sd[tid] += sd[tid + s];
                __syncthreads();
            }
            if (tid == 0) ((double*)(ws + WS_FPART))[bid * 4 + q] = sd[0];
            __syncthreads();
        }
    }
    gbar(bar, 2u * NBLK);

    // ================= PC: block 0 -> inv_norm + logits =================
    if (bid == 0) {
        double red[5] = {0, 0, 0, 0, 0};
        const double* sp = (const double*)(ws + WS_SSQ);
        for (int i = tid; i < NBLK; i += NTHR) red[4] += sp[i];
        const double* fp = (const double*)(ws + WS_FPART);
        if (tid < 32) {
            red[0] = fp[tid * 4 + 0];
            red[1] = fp[tid * 4 + 1];
            red[2] = fp[tid * 4 + 2];
            red[3] = fp[tid * 4 + 3];
        }
        double tot[5];
        __syncthreads();
        for (int q = 0; q < 5; ++q) {
            sd[tid] = red[q];
            __syncthreads();
            for (int s = 128; s; s >>= 1) {
                if (tid < s) sd[tid] += sd[tid + s];
                __syncthreads();
            }
            tot[q] = sd[0];
            __syncthreads();
        }
        if (tid == 0) {
            // ||S + lr*hh^T||^2 = ||S||^2 + 2*lr*(h^T S h) + lr^2*(||h||^2)^2
            double n2 = tot[4] + 2.0 * (double)LR * tot[0]
                      + (double)LR * (double)LR * tot[1] * tot[1];
            ws[WS_SCAL + 1] = (float)(1.0 / sqrt(n2));
            out[0] = (float)(tot[2] + (double)bc[0]);
            out[1] = (float)(tot[3] + (double)bc[1]);
        }
        __syncthreads();
    }
    gbar(bar, 3u * NBLK);

    // ====== PD: scale+write, 16 rows/block, hs in LDS, NT stores ======
    {
        f4* shs = smem4;
        const f4* hs4g = (const f4*)(ws + WS_HS);
        for (int k = tid; k < 2048; k += NTHR) shs[k] = hs4g[k];
        __syncthreads();
        float inv = ws[WS_SCAL + 1];
        const float* hsf = (const float*)shs;
#pragma unroll
        for (int r = 0; r < 16; ++r) {
            int row = bid * 16 + r;
            float hi = hsf[row] * LR;
            const f4* Srow = (const f4*)(S + (size_t)row * HD);
            float* o = out + 2 + HD + (size_t)row * HD;  // 8B-aligned -> f2 stores
            if (hi != 0.f) {
#pragma unroll
                for (int it = 0; it < 8; ++it) {
                    int j4 = it * NTHR + tid;
                    f4 s = Srow[j4];          // hope: L3 hit (S resident, NT stores don't evict)
                    f4 h = shs[j4];
                    f2 a  = {(s.x + hi * h.x) * inv, (s.y + hi * h.y) * inv};
                    f2 bb = {(s.z + hi * h.z) * inv, (s.w + hi * h.w) * inv};
                    f2* o2 = (f2*)(o + (size_t)j4 * 4);
                    __builtin_nontemporal_store(a,  o2);
                    __builtin_nontemporal_store(bb, o2 + 1);
                }
            } else {
#pragma unroll
                for (int it = 0; it < 8; ++it) {
                    int j4 = it * NTHR + tid;
                    f4 s = Srow[j4];
                    f2 a  = {s.x * inv, s.y * inv};
                    f2 bb = {s.z * inv, s.w * inv};
                    f2* o2 = (f2*)(o + (size_t)j4 * 4);
                    __builtin_nontemporal_store(a,  o2);
                    __builtin_nontemporal_store(bb, o2 + 1);
                }
            }
        }
    }
}

extern "C" void kernel_launch(void* const* d_in, const int* in_sizes, int n_in,
                              void* d_out, int out_size, void* d_ws, size_t ws_size,
                              hipStream_t stream) {
    const float* x     = (const float*)d_in[0];
    const float* W_enc = (const float*)d_in[1];
    const float* b_enc = (const float*)d_in[2];
    const float* syn   = (const float*)d_in[3];
    const float* state = (const float*)d_in[4];
    const float* W_cls = (const float*)d_in[5];
    const float* b_cls = (const float*)d_in[6];
    float* out = (float*)d_out;
    float* ws  = (float*)d_ws;

    // reset barrier + enc-done counters (graph-capturable async memset)
    hipMemsetAsync((char*)d_ws + (size_t)WS_BAR * 4, 0, 8, stream);
    hipLaunchKernelGGL(k_fused, dim3(NBLK), dim3(NTHR), 0, stream,
                       x, W_enc, b_enc, syn, state, W_cls, b_cls, out, ws);
}